// Round 1
// baseline (1605.043 us; speedup 1.0000x reference)
//
#include <hip/hip_runtime.h>

#define NN 100000
#define NE 1600000
#define EPSV 1e-5f

typedef float f32x4 __attribute__((ext_vector_type(4)));
typedef short s16x8 __attribute__((ext_vector_type(8)));

__device__ __forceinline__ unsigned short f2bf(float f) {
  unsigned int u = __float_as_uint(f);
  u += 0x7fffu + ((u >> 16) & 1u);   // round-to-nearest-even
  return (unsigned short)(u >> 16);
}

__device__ __forceinline__ ushort4 pack4(float4 v) {
  ushort4 s;
  s.x = f2bf(v.x); s.y = f2bf(v.y); s.z = f2bf(v.z); s.w = f2bf(v.w);
  return s;
}

// ---------------- scatter: sums[src] += edge_attr[e]; cnt[src] += 1 ----------------
__global__ __launch_bounds__(256) void k_scatter(
    const int* __restrict__ ei, const float4* __restrict__ ea4,
    float* __restrict__ sums, float* __restrict__ cntf) {
  int gid = blockIdx.x * 256 + threadIdx.x;   // exactly NE*16 threads
  int e = gid >> 4, q = gid & 15;
  int src = ei[e];
  float4 v = ea4[gid];
  float* dst = sums + (size_t)src * 64 + q * 4;
  unsafeAtomicAdd(dst + 0, v.x);
  unsafeAtomicAdd(dst + 1, v.y);
  unsafeAtomicAdd(dst + 2, v.z);
  unsafeAtomicAdd(dst + 3, v.w);
  if (q == 0) unsafeAtomicAdd(cntf + src, 1.0f);
}

// ---------------- GEMM1: h1 = relu([x, v_mean, state[batch]] @ W1^T + b1), stats ----------------
__global__ __launch_bounds__(256) void k_g1(
    const float4* __restrict__ x4, const float4* __restrict__ sums4,
    const float* __restrict__ cntf, const float4* __restrict__ state4,
    const int* __restrict__ batch, const float4* __restrict__ w14,
    const float* __restrict__ b1, unsigned short* __restrict__ h1,
    float* __restrict__ Sout, float* __restrict__ Qout) {
  __shared__ unsigned short lc[64][200];   // comb tile, bf16, padded
  __shared__ unsigned short lw[64][200];   // W1 (64 out rows x 192 k), bf16, padded
  __shared__ float ssum[64], ssq[64];
  const int tid = threadIdx.x;
  const int nodeBase = blockIdx.x * 64;
  if (tid < 64) { ssum[tid] = 0.f; ssq[tid] = 0.f; }
#pragma unroll
  for (int i = 0; i < 12; ++i) {           // W1: 3072 float4
    int idx = tid + i * 256;
    int row = idx / 48, q = idx % 48;
    *(ushort4*)&lw[row][q * 4] = pack4(w14[idx]);
  }
#pragma unroll
  for (int i = 0; i < 4; ++i) {            // comb: 64 nodes x 48 float4
    int idx = tid + i * 256;
    int node = idx >> 4, q = idx & 15;
    int g = nodeBase + node;
    float4 vx = {0,0,0,0}, vm = {0,0,0,0}, vs = {0,0,0,0};
    if (g < NN) {
      vx = x4[(size_t)g * 16 + q];
      float inv = 1.0f / fmaxf(cntf[g], 1.0f);
      float4 s = sums4[(size_t)g * 16 + q];
      vm.x = s.x * inv; vm.y = s.y * inv; vm.z = s.z * inv; vm.w = s.w * inv;
      int b = batch[g];
      vs = state4[b * 16 + q];
    }
    *(ushort4*)&lc[node][q * 4]       = pack4(vx);
    *(ushort4*)&lc[node][64 + q * 4]  = pack4(vm);
    *(ushort4*)&lc[node][128 + q * 4] = pack4(vs);
  }
  __syncthreads();
  const int lane = tid & 63, w = tid >> 6;
  const int rg = lane >> 4, ci = lane & 15;
  f32x4 acc[4] = {{0,0,0,0},{0,0,0,0},{0,0,0,0},{0,0,0,0}};
#pragma unroll
  for (int s = 0; s < 6; ++s) {
    int k0 = 32 * s + rg * 8;
    s16x8 a = *(const s16x8*)&lc[w * 16 + ci][k0];
#pragma unroll
    for (int c = 0; c < 4; ++c) {
      s16x8 b = *(const s16x8*)&lw[c * 16 + ci][k0];
      acc[c] = __builtin_amdgcn_mfma_f32_16x16x32_bf16(a, b, acc[c], 0, 0, 0);
    }
  }
#pragma unroll
  for (int c = 0; c < 4; ++c) {
    int col = c * 16 + ci;
    float bb = b1[col];
    float ls = 0.f, lq = 0.f;
#pragma unroll
    for (int r = 0; r < 4; ++r) {
      int g = nodeBase + w * 16 + rg * 4 + r;
      if (g < NN) {
        float v = fmaxf(acc[c][r] + bb, 0.f);
        h1[(size_t)g * 64 + col] = f2bf(v);
        ls += v; lq += v * v;
      }
    }
    atomicAdd(&ssum[col], ls);
    atomicAdd(&ssq[col], lq);
  }
  __syncthreads();
  if (tid < 64) {
    unsafeAtomicAdd(&Sout[tid], ssum[tid]);
    unsafeAtomicAdd(&Qout[tid], ssq[tid]);
  }
}

// ---------------- GEMM2/3 with BN folded into weights ----------------
template <bool RELU, bool OUTF32>
__global__ __launch_bounds__(256) void k_gemm64(
    const s16x8* __restrict__ A8,     // bf16 [NN][64]
    const float4* __restrict__ w4,    // f32 [64][64] (out j, k)
    const float* __restrict__ bias,
    const float* __restrict__ gm, const float* __restrict__ bt,
    const float* __restrict__ Sin, const float* __restrict__ Qin,
    unsigned short* __restrict__ Obf, float* __restrict__ Of32,
    float* __restrict__ Sout, float* __restrict__ Qout) {
  __shared__ unsigned short la[64][72];
  __shared__ unsigned short lwf[64][72];
  __shared__ float lA[64], lC[64], lD[64], ssum[64], ssq[64];
  const int tid = threadIdx.x;
  const int nodeBase = blockIdx.x * 64;
  if (tid < 64) {
    float mu = Sin[tid] * (1.0f / NN);
    float var = Qin[tid] * (1.0f / NN) - mu * mu;
    float a = gm[tid] * rsqrtf(var + EPSV);
    lA[tid] = a;
    lC[tid] = bt[tid] - mu * a;
    ssum[tid] = 0.f; ssq[tid] = 0.f;
  }
  __syncthreads();
#pragma unroll
  for (int i = 0; i < 2; ++i) {            // A tile: 512 x 16B
    int idx = tid + i * 256;
    int row = idx >> 3, q = idx & 7;
    int g = nodeBase + row;
    s16x8 v = {};
    if (g < NN) v = A8[(size_t)g * 8 + q];
    *(s16x8*)&la[row][q * 8] = v;
  }
#pragma unroll
  for (int i = 0; i < 4; ++i) {            // fold W by BN scale a_k
    int idx = tid + i * 256;
    int j = idx >> 4, q = idx & 15;
    float4 v = w4[idx];
    int k = q * 4;
    ushort4 s;
    s.x = f2bf(v.x * lA[k]);     s.y = f2bf(v.y * lA[k + 1]);
    s.z = f2bf(v.z * lA[k + 2]); s.w = f2bf(v.w * lA[k + 3]);
    *(ushort4*)&lwf[j][k] = s;
  }
  if (tid < 64) {                          // folded bias d_j = b_j + sum_k c_k W[j][k]
    const float* W = (const float*)w4 + tid * 64;
    float d = bias[tid];
    for (int k = 0; k < 64; ++k) d += lC[k] * W[k];
    lD[tid] = d;
  }
  __syncthreads();
  const int lane = tid & 63, w = tid >> 6;
  const int rg = lane >> 4, ci = lane & 15;
  f32x4 acc[4] = {{0,0,0,0},{0,0,0,0},{0,0,0,0},{0,0,0,0}};
#pragma unroll
  for (int s = 0; s < 2; ++s) {
    int k0 = 32 * s + rg * 8;
    s16x8 a = *(const s16x8*)&la[w * 16 + ci][k0];
#pragma unroll
    for (int c = 0; c < 4; ++c) {
      s16x8 b = *(const s16x8*)&lwf[c * 16 + ci][k0];
      acc[c] = __builtin_amdgcn_mfma_f32_16x16x32_bf16(a, b, acc[c], 0, 0, 0);
    }
  }
#pragma unroll
  for (int c = 0; c < 4; ++c) {
    int col = c * 16 + ci;
    float dd = lD[col];
    float ls = 0.f, lq = 0.f;
#pragma unroll
    for (int r = 0; r < 4; ++r) {
      int g = nodeBase + w * 16 + rg * 4 + r;
      if (g < NN) {
        float v = acc[c][r] + dd;
        if (RELU) v = fmaxf(v, 0.f);
        if (OUTF32) Of32[(size_t)g * 64 + col] = v;
        else        Obf[(size_t)g * 64 + col] = f2bf(v);
        ls += v; lq += v * v;
      }
    }
    atomicAdd(&ssum[col], ls);
    atomicAdd(&ssq[col], lq);
  }
  __syncthreads();
  if (tid < 64) {
    unsafeAtomicAdd(&Sout[tid], ssum[tid]);
    unsafeAtomicAdd(&Qout[tid], ssq[tid]);
  }
}

// ---------------- final BN3 elementwise ----------------
__global__ __launch_bounds__(256) void k_bn3(
    const float4* __restrict__ h3, const float* __restrict__ gm,
    const float* __restrict__ bt, const float* __restrict__ S,
    const float* __restrict__ Q, float4* __restrict__ out) {
  __shared__ float lA[64], lC[64];
  const int tid = threadIdx.x;
  if (tid < 64) {
    float mu = S[tid] * (1.0f / NN);
    float var = Q[tid] * (1.0f / NN) - mu * mu;
    float a = gm[tid] * rsqrtf(var + EPSV);
    lA[tid] = a;
    lC[tid] = bt[tid] - mu * a;
  }
  __syncthreads();
  const int total = NN * 16;
  for (int idx = blockIdx.x * 256 + tid; idx < total; idx += gridDim.x * 256) {
    float4 v = h3[idx];
    int k = (idx & 15) * 4;
    v.x = v.x * lA[k]     + lC[k];
    v.y = v.y * lA[k + 1] + lC[k + 1];
    v.z = v.z * lA[k + 2] + lC[k + 2];
    v.w = v.w * lA[k + 3] + lC[k + 3];
    out[idx] = v;
  }
}

extern "C" void kernel_launch(void* const* d_in, const int* in_sizes, int n_in,
                              void* d_out, int out_size, void* d_ws, size_t ws_size,
                              hipStream_t stream) {
  const float* x     = (const float*)d_in[0];
  const int*   ei    = (const int*)d_in[1];
  const float* ea    = (const float*)d_in[2];
  const float* state = (const float*)d_in[3];
  const int*   batch = (const int*)d_in[4];
  const float* W1  = (const float*)d_in[5];
  const float* b1  = (const float*)d_in[6];
  const float* g1  = (const float*)d_in[7];
  const float* be1 = (const float*)d_in[8];
  const float* W2  = (const float*)d_in[9];
  const float* b2  = (const float*)d_in[10];
  const float* g2  = (const float*)d_in[11];
  const float* be2 = (const float*)d_in[12];
  const float* W3  = (const float*)d_in[13];
  const float* b3  = (const float*)d_in[14];
  const float* g3  = (const float*)d_in[15];
  const float* be3 = (const float*)d_in[16];

  char* ws = (char*)d_ws;
  float* sums = (float*)ws;                              // 25,600,000 B
  float* cntf = (float*)(ws + 25600000);                 //    400,000 B
  float* S1   = (float*)(ws + 26000000);                 // 6 x 64 f32
  float* Q1 = S1 + 64;
  float* S2 = S1 + 128;
  float* Q2 = S1 + 192;
  float* S3 = S1 + 256;
  float* Q3 = S1 + 320;
  unsigned short* h1 = (unsigned short*)(ws + 26001536); // 12,800,000 B (bf16)
  unsigned short* h2 = (unsigned short*)(ws + 38801536); // 12,800,000 B (bf16)
  float*          h3 = (float*)(ws + 51601536);          // 25,600,000 B (f32)

  // zero accumulators (sums + cnt + stats)
  hipMemsetAsync(ws, 0, 26001536, stream);

  k_scatter<<<NE * 16 / 256, 256, 0, stream>>>(ei, (const float4*)ea, sums, cntf);

  const int nblk = (NN + 63) / 64;   // 1563
  k_g1<<<nblk, 256, 0, stream>>>((const float4*)x, (const float4*)sums, cntf,
                                 (const float4*)state, batch, (const float4*)W1,
                                 b1, h1, S1, Q1);
  k_gemm64<true, false><<<nblk, 256, 0, stream>>>(
      (const s16x8*)h1, (const float4*)W2, b2, g1, be1, S1, Q1, h2, nullptr, S2, Q2);
  k_gemm64<false, true><<<nblk, 256, 0, stream>>>(
      (const s16x8*)h2, (const float4*)W3, b3, g2, be2, S2, Q2, nullptr, h3, S3, Q3);
  k_bn3<<<2048, 256, 0, stream>>>((const float4*)h3, g3, be3, S3, Q3, (float4*)d_out);
}

// Round 2
// 399.466 us; speedup vs baseline: 4.0180x; 4.0180x over previous
//
#include <hip/hip_runtime.h>

#define NN 100000
#define NE 1600000
#define EPSV 1e-5f

typedef float f32x4 __attribute__((ext_vector_type(4)));
typedef short s16x8 __attribute__((ext_vector_type(8)));

__device__ __forceinline__ unsigned short f2bf(float f) {
  unsigned int u = __float_as_uint(f);
  u += 0x7fffu + ((u >> 16) & 1u);   // round-to-nearest-even
  return (unsigned short)(u >> 16);
}

__device__ __forceinline__ ushort4 pack4(float4 v) {
  ushort4 s;
  s.x = f2bf(v.x); s.y = f2bf(v.y); s.z = f2bf(v.z); s.w = f2bf(v.w);
  return s;
}

// ---------------- bucket: eids[src][pos] = e (padded width 64) ----------------
__global__ __launch_bounds__(256) void k_bucket(
    const int* __restrict__ ei, int* __restrict__ cnt, int* __restrict__ eids) {
  int e = blockIdx.x * 256 + threadIdx.x;   // exactly NE threads
  int src = ei[e];
  int pos = atomicAdd(&cnt[src], 1);
  if (pos < 64) eids[(size_t)src * 64 + pos] = e;
}

// ---------------- gather: vmean[n] = mean of edge_attr rows in n's list ----------------
__global__ __launch_bounds__(256) void k_gather(
    const int* __restrict__ cnt, const int* __restrict__ eids,
    const float* __restrict__ ea, float* __restrict__ vmean) {
  int n = __builtin_amdgcn_readfirstlane(blockIdx.x * 4 + (threadIdx.x >> 6));
  int lane = threadIdx.x & 63;
  const int* elist = eids + (size_t)n * 64;
  int c = cnt[n];
  int m = c < 64 ? c : 64;
  float a0 = 0.f, a1 = 0.f, a2 = 0.f, a3 = 0.f;
  int e = 0;
  for (; e + 4 <= m; e += 4) {
    int i0 = elist[e], i1 = elist[e + 1], i2 = elist[e + 2], i3 = elist[e + 3];
    a0 += ea[(size_t)i0 * 64 + lane];
    a1 += ea[(size_t)i1 * 64 + lane];
    a2 += ea[(size_t)i2 * 64 + lane];
    a3 += ea[(size_t)i3 * 64 + lane];
  }
  for (; e < m; ++e) a0 += ea[(size_t)elist[e] * 64 + lane];
  float inv = 1.0f / fmaxf((float)c, 1.0f);
  vmean[(size_t)n * 64 + lane] = (a0 + a1 + a2 + a3) * inv;
}

// ---------------- GEMM1: h1 = relu([x, v_mean, state[batch]] @ W1^T + b1), stats ----------------
__global__ __launch_bounds__(256) void k_g1(
    const float4* __restrict__ x4, const float4* __restrict__ vmean4,
    const float4* __restrict__ state4,
    const int* __restrict__ batch, const float4* __restrict__ w14,
    const float* __restrict__ b1, unsigned short* __restrict__ h1,
    float* __restrict__ Sout, float* __restrict__ Qout) {
  __shared__ unsigned short lc[64][200];   // comb tile, bf16, padded
  __shared__ unsigned short lw[64][200];   // W1 (64 out rows x 192 k), bf16, padded
  __shared__ float ssum[64], ssq[64];
  const int tid = threadIdx.x;
  const int nodeBase = blockIdx.x * 64;
  if (tid < 64) { ssum[tid] = 0.f; ssq[tid] = 0.f; }
#pragma unroll
  for (int i = 0; i < 12; ++i) {           // W1: 3072 float4
    int idx = tid + i * 256;
    int row = idx / 48, q = idx % 48;
    *(ushort4*)&lw[row][q * 4] = pack4(w14[idx]);
  }
#pragma unroll
  for (int i = 0; i < 4; ++i) {            // comb: 64 nodes x 48 float4
    int idx = tid + i * 256;
    int node = idx >> 4, q = idx & 15;
    int g = nodeBase + node;
    float4 vx = {0,0,0,0}, vm = {0,0,0,0}, vs = {0,0,0,0};
    if (g < NN) {
      vx = x4[(size_t)g * 16 + q];
      vm = vmean4[(size_t)g * 16 + q];
      int b = batch[g];
      vs = state4[b * 16 + q];
    }
    *(ushort4*)&lc[node][q * 4]       = pack4(vx);
    *(ushort4*)&lc[node][64 + q * 4]  = pack4(vm);
    *(ushort4*)&lc[node][128 + q * 4] = pack4(vs);
  }
  __syncthreads();
  const int lane = tid & 63, w = tid >> 6;
  const int rg = lane >> 4, ci = lane & 15;
  f32x4 acc[4] = {{0,0,0,0},{0,0,0,0},{0,0,0,0},{0,0,0,0}};
#pragma unroll
  for (int s = 0; s < 6; ++s) {
    int k0 = 32 * s + rg * 8;
    s16x8 a = *(const s16x8*)&lc[w * 16 + ci][k0];
#pragma unroll
    for (int c = 0; c < 4; ++c) {
      s16x8 b = *(const s16x8*)&lw[c * 16 + ci][k0];
      acc[c] = __builtin_amdgcn_mfma_f32_16x16x32_bf16(a, b, acc[c], 0, 0, 0);
    }
  }
#pragma unroll
  for (int c = 0; c < 4; ++c) {
    int col = c * 16 + ci;
    float bb = b1[col];
    float ls = 0.f, lq = 0.f;
#pragma unroll
    for (int r = 0; r < 4; ++r) {
      int g = nodeBase + w * 16 + rg * 4 + r;
      if (g < NN) {
        float v = fmaxf(acc[c][r] + bb, 0.f);
        h1[(size_t)g * 64 + col] = f2bf(v);
        ls += v; lq += v * v;
      }
    }
    atomicAdd(&ssum[col], ls);
    atomicAdd(&ssq[col], lq);
  }
  __syncthreads();
  if (tid < 64) {
    unsafeAtomicAdd(&Sout[tid], ssum[tid]);
    unsafeAtomicAdd(&Qout[tid], ssq[tid]);
  }
}

// ---------------- GEMM2/3 with BN folded into weights ----------------
template <bool RELU, bool OUTF32>
__global__ __launch_bounds__(256) void k_gemm64(
    const s16x8* __restrict__ A8,     // bf16 [NN][64]
    const float4* __restrict__ w4,    // f32 [64][64] (out j, k)
    const float* __restrict__ bias,
    const float* __restrict__ gm, const float* __restrict__ bt,
    const float* __restrict__ Sin, const float* __restrict__ Qin,
    unsigned short* __restrict__ Obf, float* __restrict__ Of32,
    float* __restrict__ Sout, float* __restrict__ Qout) {
  __shared__ unsigned short la[64][72];
  __shared__ unsigned short lwf[64][72];
  __shared__ float lA[64], lC[64], lD[64], ssum[64], ssq[64];
  const int tid = threadIdx.x;
  const int nodeBase = blockIdx.x * 64;
  if (tid < 64) {
    float mu = Sin[tid] * (1.0f / NN);
    float var = Qin[tid] * (1.0f / NN) - mu * mu;
    float a = gm[tid] * rsqrtf(var + EPSV);
    lA[tid] = a;
    lC[tid] = bt[tid] - mu * a;
    ssum[tid] = 0.f; ssq[tid] = 0.f;
  }
  __syncthreads();
#pragma unroll
  for (int i = 0; i < 2; ++i) {            // A tile: 512 x 16B
    int idx = tid + i * 256;
    int row = idx >> 3, q = idx & 7;
    int g = nodeBase + row;
    s16x8 v = {};
    if (g < NN) v = A8[(size_t)g * 8 + q];
    *(s16x8*)&la[row][q * 8] = v;
  }
#pragma unroll
  for (int i = 0; i < 4; ++i) {            // fold W by BN scale a_k
    int idx = tid + i * 256;
    int j = idx >> 4, q = idx & 15;
    float4 v = w4[idx];
    int k = q * 4;
    ushort4 s;
    s.x = f2bf(v.x * lA[k]);     s.y = f2bf(v.y * lA[k + 1]);
    s.z = f2bf(v.z * lA[k + 2]); s.w = f2bf(v.w * lA[k + 3]);
    *(ushort4*)&lwf[j][k] = s;
  }
  if (tid < 64) {                          // folded bias d_j = b_j + sum_k c_k W[j][k]
    const float* W = (const float*)w4 + tid * 64;
    float d = bias[tid];
    for (int k = 0; k < 64; ++k) d += lC[k] * W[k];
    lD[tid] = d;
  }
  __syncthreads();
  const int lane = tid & 63, w = tid >> 6;
  const int rg = lane >> 4, ci = lane & 15;
  f32x4 acc[4] = {{0,0,0,0},{0,0,0,0},{0,0,0,0},{0,0,0,0}};
#pragma unroll
  for (int s = 0; s < 2; ++s) {
    int k0 = 32 * s + rg * 8;
    s16x8 a = *(const s16x8*)&la[w * 16 + ci][k0];
#pragma unroll
    for (int c = 0; c < 4; ++c) {
      s16x8 b = *(const s16x8*)&lwf[c * 16 + ci][k0];
      acc[c] = __builtin_amdgcn_mfma_f32_16x16x32_bf16(a, b, acc[c], 0, 0, 0);
    }
  }
#pragma unroll
  for (int c = 0; c < 4; ++c) {
    int col = c * 16 + ci;
    float dd = lD[col];
    float ls = 0.f, lq = 0.f;
#pragma unroll
    for (int r = 0; r < 4; ++r) {
      int g = nodeBase + w * 16 + rg * 4 + r;
      if (g < NN) {
        float v = acc[c][r] + dd;
        if (RELU) v = fmaxf(v, 0.f);
        if (OUTF32) Of32[(size_t)g * 64 + col] = v;
        else        Obf[(size_t)g * 64 + col] = f2bf(v);
        ls += v; lq += v * v;
      }
    }
    atomicAdd(&ssum[col], ls);
    atomicAdd(&ssq[col], lq);
  }
  __syncthreads();
  if (tid < 64) {
    unsafeAtomicAdd(&Sout[tid], ssum[tid]);
    unsafeAtomicAdd(&Qout[tid], ssq[tid]);
  }
}

// ---------------- final BN3 elementwise ----------------
__global__ __launch_bounds__(256) void k_bn3(
    const float4* __restrict__ h3, const float* __restrict__ gm,
    const float* __restrict__ bt, const float* __restrict__ S,
    const float* __restrict__ Q, float4* __restrict__ out) {
  __shared__ float lA[64], lC[64];
  const int tid = threadIdx.x;
  if (tid < 64) {
    float mu = S[tid] * (1.0f / NN);
    float var = Q[tid] * (1.0f / NN) - mu * mu;
    float a = gm[tid] * rsqrtf(var + EPSV);
    lA[tid] = a;
    lC[tid] = bt[tid] - mu * a;
  }
  __syncthreads();
  const int total = NN * 16;
  for (int idx = blockIdx.x * 256 + tid; idx < total; idx += gridDim.x * 256) {
    float4 v = h3[idx];
    int k = (idx & 15) * 4;
    v.x = v.x * lA[k]     + lC[k];
    v.y = v.y * lA[k + 1] + lC[k + 1];
    v.z = v.z * lA[k + 2] + lC[k + 2];
    v.w = v.w * lA[k + 3] + lC[k + 3];
    out[idx] = v;
  }
}

extern "C" void kernel_launch(void* const* d_in, const int* in_sizes, int n_in,
                              void* d_out, int out_size, void* d_ws, size_t ws_size,
                              hipStream_t stream) {
  const float* x     = (const float*)d_in[0];
  const int*   ei    = (const int*)d_in[1];
  const float* ea    = (const float*)d_in[2];
  const float* state = (const float*)d_in[3];
  const int*   batch = (const int*)d_in[4];
  const float* W1  = (const float*)d_in[5];
  const float* b1  = (const float*)d_in[6];
  const float* g1  = (const float*)d_in[7];
  const float* be1 = (const float*)d_in[8];
  const float* W2  = (const float*)d_in[9];
  const float* b2  = (const float*)d_in[10];
  const float* g2  = (const float*)d_in[11];
  const float* be2 = (const float*)d_in[12];
  const float* W3  = (const float*)d_in[13];
  const float* b3  = (const float*)d_in[14];
  const float* g3  = (const float*)d_in[15];
  const float* be3 = (const float*)d_in[16];

  // Workspace layout (16B aligned), with aliasing:
  //   [0,        400000)   cnt (int, per-node degree)          } memset
  //   [400000,   401536)   stats S1..Q3 (6 x 64 f32)           } memset
  //   [401536, 26001536)   eids (int, padded 64/node)  == h3 (f32) alias
  //   [26001536,51601536)  vmean (f32)                 == h2 (bf16) alias (first half)
  //   [51601536,64401536)  h1 (bf16)
  char* ws = (char*)d_ws;
  int*   cnt  = (int*)ws;
  float* S1   = (float*)(ws + 400000);
  float* Q1 = S1 + 64;
  float* S2 = S1 + 128;
  float* Q2 = S1 + 192;
  float* S3 = S1 + 256;
  float* Q3 = S1 + 320;
  int*            eids  = (int*)(ws + 401536);
  float*          h3    = (float*)(ws + 401536);           // alias eids (dead after gather)
  float*          vmean = (float*)(ws + 26001536);
  unsigned short* h2    = (unsigned short*)(ws + 26001536); // alias vmean (dead after g1)
  unsigned short* h1    = (unsigned short*)(ws + 51601536);

  hipMemsetAsync(ws, 0, 401536, stream);   // cnt + stats

  k_bucket<<<NE / 256, 256, 0, stream>>>(ei, cnt, eids);
  k_gather<<<NN / 4, 256, 0, stream>>>(cnt, eids, ea, vmean);

  const int nblk = (NN + 63) / 64;   // 1563
  k_g1<<<nblk, 256, 0, stream>>>((const float4*)x, (const float4*)vmean,
                                 (const float4*)state, batch, (const float4*)W1,
                                 b1, h1, S1, Q1);
  k_gemm64<true, false><<<nblk, 256, 0, stream>>>(
      (const s16x8*)h1, (const float4*)W2, b2, g1, be1, S1, Q1, h2, nullptr, S2, Q2);
  k_gemm64<false, true><<<nblk, 256, 0, stream>>>(
      (const s16x8*)h2, (const float4*)W3, b3, g2, be2, S2, Q2, nullptr, h3, S3, Q3);
  k_bn3<<<2048, 256, 0, stream>>>((const float4*)h3, g3, be3, S3, Q3, (float4*)d_out);
}

// Round 3
// 385.658 us; speedup vs baseline: 4.1618x; 1.0358x over previous
//
#include <hip/hip_runtime.h>

#define NN 100000
#define NE 1600000
#define EPSV 1e-5f

typedef float f32x4 __attribute__((ext_vector_type(4)));
typedef short s16x8 __attribute__((ext_vector_type(8)));

__device__ __forceinline__ unsigned short f2bf(float f) {
  unsigned int u = __float_as_uint(f);
  u += 0x7fffu + ((u >> 16) & 1u);   // round-to-nearest-even
  return (unsigned short)(u >> 16);
}

__device__ __forceinline__ float bf2f(unsigned short s) {
  return __uint_as_float(((unsigned int)s) << 16);
}

__device__ __forceinline__ ushort4 pack4(float4 v) {
  ushort4 s;
  s.x = f2bf(v.x); s.y = f2bf(v.y); s.z = f2bf(v.z); s.w = f2bf(v.w);
  return s;
}

// ---------------- bucket: eids[src][pos] = e (padded width 64) ----------------
__global__ __launch_bounds__(256) void k_bucket(
    const int* __restrict__ ei, int* __restrict__ cnt, int* __restrict__ eids) {
  int e = blockIdx.x * 256 + threadIdx.x;   // exactly NE threads
  int src = ei[e];
  int pos = atomicAdd(&cnt[src], 1);
  if (pos < 64) eids[(size_t)src * 64 + pos] = e;
}

// ---------------- gather: vmb[n] = bf16 mean of edge_attr rows of node n ----------------
// wave per node; lane = (row-group grp = lane>>4, float4-chunk q = lane&15)
// 16 rows in flight per iteration via 4 independent streams.
__global__ __launch_bounds__(256) void k_gather(
    const int* __restrict__ cnt, const int* __restrict__ eids,
    const float4* __restrict__ ea4, ushort4* __restrict__ vmb4) {
  int n = __builtin_amdgcn_readfirstlane(blockIdx.x * 4 + (threadIdx.x >> 6));
  int lane = threadIdx.x & 63;
  int grp = lane >> 4, q = lane & 15;
  const int* elist = eids + (size_t)n * 64;
  int c = cnt[n];
  int m = c < 64 ? c : 64;
  float ax = 0.f, ay = 0.f, az = 0.f, aw = 0.f;
  for (int e = 0; e < m; e += 16) {
    int rm = m - 1;
    int r0 = e + grp, r1 = e + 4 + grp, r2 = e + 8 + grp, r3 = e + 12 + grp;
    int i0 = elist[r0 < m ? r0 : rm];
    int i1 = elist[r1 < m ? r1 : rm];
    int i2 = elist[r2 < m ? r2 : rm];
    int i3 = elist[r3 < m ? r3 : rm];
    float4 v0 = ea4[(size_t)i0 * 16 + q];
    float4 v1 = ea4[(size_t)i1 * 16 + q];
    float4 v2 = ea4[(size_t)i2 * 16 + q];
    float4 v3 = ea4[(size_t)i3 * 16 + q];
    float m0 = r0 < m ? 1.f : 0.f, m1 = r1 < m ? 1.f : 0.f;
    float m2 = r2 < m ? 1.f : 0.f, m3 = r3 < m ? 1.f : 0.f;
    ax += m0 * v0.x + m1 * v1.x + m2 * v2.x + m3 * v3.x;
    ay += m0 * v0.y + m1 * v1.y + m2 * v2.y + m3 * v3.y;
    az += m0 * v0.z + m1 * v1.z + m2 * v2.z + m3 * v3.z;
    aw += m0 * v0.w + m1 * v1.w + m2 * v2.w + m3 * v3.w;
  }
  // reduce across the 4 row-groups (lanes with same q)
  ax += __shfl_xor(ax, 16); ay += __shfl_xor(ay, 16);
  az += __shfl_xor(az, 16); aw += __shfl_xor(aw, 16);
  ax += __shfl_xor(ax, 32); ay += __shfl_xor(ay, 32);
  az += __shfl_xor(az, 32); aw += __shfl_xor(aw, 32);
  if (lane < 16) {
    float inv = 1.0f / fmaxf((float)c, 1.0f);
    float4 r; r.x = ax * inv; r.y = ay * inv; r.z = az * inv; r.w = aw * inv;
    vmb4[(size_t)n * 16 + lane] = pack4(r);
  }
}

// ---------------- GEMM1: h1 = relu([x, v_mean, state[batch]] @ W1^T + b1), stats ----------------
__global__ __launch_bounds__(256) void k_g1(
    const float4* __restrict__ x4, const ushort4* __restrict__ vmb4,
    const float4* __restrict__ state4,
    const int* __restrict__ batch, const float4* __restrict__ w14,
    const float* __restrict__ b1, unsigned short* __restrict__ h1,
    float* __restrict__ Sout, float* __restrict__ Qout) {
  __shared__ unsigned short lc[64][200];   // comb tile, bf16, padded
  __shared__ unsigned short lw[64][200];   // W1 (64 out rows x 192 k), bf16; reused as out-tile
  __shared__ float ssum[64], ssq[64];
  const int tid = threadIdx.x;
  const int nodeBase = blockIdx.x * 64;
  if (tid < 64) { ssum[tid] = 0.f; ssq[tid] = 0.f; }
#pragma unroll
  for (int i = 0; i < 12; ++i) {           // W1: 3072 float4
    int idx = tid + i * 256;
    int row = idx / 48, q = idx % 48;
    *(ushort4*)&lw[row][q * 4] = pack4(w14[idx]);
  }
#pragma unroll
  for (int i = 0; i < 4; ++i) {            // comb: 64 nodes x 16 chunks
    int idx = tid + i * 256;
    int node = idx >> 4, q = idx & 15;
    int g = nodeBase + node;
    float4 vx = {0,0,0,0}, vs = {0,0,0,0};
    ushort4 vm = {0,0,0,0};
    if (g < NN) {
      vx = x4[(size_t)g * 16 + q];
      vm = vmb4[(size_t)g * 16 + q];
      int b = batch[g];
      vs = state4[b * 16 + q];
    }
    *(ushort4*)&lc[node][q * 4]       = pack4(vx);
    *(ushort4*)&lc[node][64 + q * 4]  = vm;
    *(ushort4*)&lc[node][128 + q * 4] = pack4(vs);
  }
  __syncthreads();
  const int lane = tid & 63, w = tid >> 6;
  const int rg = lane >> 4, ci = lane & 15;
  f32x4 acc[4] = {{0,0,0,0},{0,0,0,0},{0,0,0,0},{0,0,0,0}};
#pragma unroll
  for (int s = 0; s < 6; ++s) {
    int k0 = 32 * s + rg * 8;
    s16x8 a = *(const s16x8*)&lc[w * 16 + ci][k0];
#pragma unroll
    for (int c = 0; c < 4; ++c) {
      s16x8 b = *(const s16x8*)&lw[c * 16 + ci][k0];
      acc[c] = __builtin_amdgcn_mfma_f32_16x16x32_bf16(a, b, acc[c], 0, 0, 0);
    }
  }
  __syncthreads();                         // all MFMAs done; reuse lw as out-tile
  unsigned short (*lo)[72] = (unsigned short(*)[72])lw;
#pragma unroll
  for (int c = 0; c < 4; ++c) {
    int col = c * 16 + ci;
    float bb = b1[col];
    float ls = 0.f, lq = 0.f;
#pragma unroll
    for (int r = 0; r < 4; ++r) {
      int row = w * 16 + rg * 4 + r;
      float v = fmaxf(acc[c][r] + bb, 0.f);
      lo[row][col] = f2bf(v);
      if (nodeBase + row < NN) { ls += v; lq += v * v; }
    }
    atomicAdd(&ssum[col], ls);
    atomicAdd(&ssq[col], lq);
  }
  __syncthreads();
#pragma unroll
  for (int i = 0; i < 2; ++i) {            // coalesced 16B stores of the 64x64 tile
    int idx = tid + i * 256;
    int row = idx >> 3, q = idx & 7;
    int g = nodeBase + row;
    if (g < NN) *(s16x8*)&h1[(size_t)g * 64 + q * 8] = *(const s16x8*)&lo[row][q * 8];
  }
  if (tid < 64) {
    unsafeAtomicAdd(&Sout[tid], ssum[tid]);
    unsafeAtomicAdd(&Qout[tid], ssq[tid]);
  }
}

// ---------------- prep: fold BN(prev) into next-layer weights (one block) ----------------
__global__ __launch_bounds__(256) void k_prep(
    const float* __restrict__ Sin, const float* __restrict__ Qin,
    const float* __restrict__ gm, const float* __restrict__ bt,
    const float* __restrict__ W, const float* __restrict__ bias,
    unsigned short* __restrict__ wf, float* __restrict__ dout) {
  __shared__ float lA[64], lC[64], red[256];
  int t = threadIdx.x;
  if (t < 64) {
    float mu = Sin[t] * (1.0f / NN);
    float var = Qin[t] * (1.0f / NN) - mu * mu;
    float a = gm[t] * rsqrtf(var + EPSV);
    lA[t] = a;
    lC[t] = bt[t] - mu * a;
  }
  __syncthreads();
#pragma unroll
  for (int i = 0; i < 16; ++i) {           // fold 64x64 weights
    int idx = t + i * 256;
    wf[idx] = f2bf(W[idx] * lA[idx & 63]);
  }
  int j = t >> 2, p = t & 3;               // folded bias: d_j = b_j + sum_k c_k W[j][k]
  const float* Wr = W + j * 64 + p * 16;
  float s = 0.f;
#pragma unroll
  for (int k = 0; k < 16; ++k) s += lC[p * 16 + k] * Wr[k];
  red[t] = s;
  __syncthreads();
  if (t < 64) dout[t] = bias[t] + red[t * 4] + red[t * 4 + 1] + red[t * 4 + 2] + red[t * 4 + 3];
}

// ---------------- GEMM2/3: out = [relu](A @ Wf^T + d), stats ----------------
template <bool RELU>
__global__ __launch_bounds__(256) void k_gemm64(
    const s16x8* __restrict__ A8,     // bf16 [NN][64]
    const s16x8* __restrict__ w8,     // bf16 [64][64] folded
    const float* __restrict__ d,      // folded bias
    unsigned short* __restrict__ Obf,
    float* __restrict__ Sout, float* __restrict__ Qout) {
  __shared__ unsigned short la[64][72];    // A tile; reused as out-tile
  __shared__ unsigned short lwf[64][72];
  __shared__ float ssum[64], ssq[64];
  const int tid = threadIdx.x;
  const int nodeBase = blockIdx.x * 64;
  if (tid < 64) { ssum[tid] = 0.f; ssq[tid] = 0.f; }
#pragma unroll
  for (int i = 0; i < 2; ++i) {            // A tile: 512 x 16B
    int idx = tid + i * 256;
    int row = idx >> 3, q = idx & 7;
    int g = nodeBase + row;
    s16x8 v = {};
    if (g < NN) v = A8[(size_t)g * 8 + q];
    *(s16x8*)&la[row][q * 8] = v;
  }
#pragma unroll
  for (int i = 0; i < 2; ++i) {            // W tile (already folded bf16)
    int idx = tid + i * 256;
    int j = idx >> 3, q = idx & 7;
    *(s16x8*)&lwf[j][q * 8] = w8[idx];
  }
  __syncthreads();
  const int lane = tid & 63, w = tid >> 6;
  const int rg = lane >> 4, ci = lane & 15;
  f32x4 acc[4] = {{0,0,0,0},{0,0,0,0},{0,0,0,0},{0,0,0,0}};
#pragma unroll
  for (int s = 0; s < 2; ++s) {
    int k0 = 32 * s + rg * 8;
    s16x8 a = *(const s16x8*)&la[w * 16 + ci][k0];
#pragma unroll
    for (int c = 0; c < 4; ++c) {
      s16x8 b = *(const s16x8*)&lwf[c * 16 + ci][k0];
      acc[c] = __builtin_amdgcn_mfma_f32_16x16x32_bf16(a, b, acc[c], 0, 0, 0);
    }
  }
  __syncthreads();                         // reuse la as out-tile
  unsigned short (*lo)[72] = (unsigned short(*)[72])la;
#pragma unroll
  for (int c = 0; c < 4; ++c) {
    int col = c * 16 + ci;
    float dd = d[col];
    float ls = 0.f, lq = 0.f;
#pragma unroll
    for (int r = 0; r < 4; ++r) {
      int row = w * 16 + rg * 4 + r;
      float v = acc[c][r] + dd;
      if (RELU) v = fmaxf(v, 0.f);
      lo[row][col] = f2bf(v);
      if (nodeBase + row < NN) { ls += v; lq += v * v; }
    }
    atomicAdd(&ssum[col], ls);
    atomicAdd(&ssq[col], lq);
  }
  __syncthreads();
#pragma unroll
  for (int i = 0; i < 2; ++i) {
    int idx = tid + i * 256;
    int row = idx >> 3, q = idx & 7;
    int g = nodeBase + row;
    if (g < NN) *(s16x8*)&Obf[(size_t)g * 64 + q * 8] = *(const s16x8*)&lo[row][q * 8];
  }
  if (tid < 64) {
    unsafeAtomicAdd(&Sout[tid], ssum[tid]);
    unsafeAtomicAdd(&Qout[tid], ssq[tid]);
  }
}

// ---------------- final BN3 elementwise (bf16 in, f32 out) ----------------
__global__ __launch_bounds__(256) void k_bn3(
    const s16x8* __restrict__ h3b, const float* __restrict__ gm,
    const float* __restrict__ bt, const float* __restrict__ S,
    const float* __restrict__ Q, float4* __restrict__ out) {
  __shared__ float lA[64], lC[64];
  const int tid = threadIdx.x;
  if (tid < 64) {
    float mu = S[tid] * (1.0f / NN);
    float var = Q[tid] * (1.0f / NN) - mu * mu;
    float a = gm[tid] * rsqrtf(var + EPSV);
    lA[tid] = a;
    lC[tid] = bt[tid] - mu * a;
  }
  __syncthreads();
  const int total = NN * 8;                // short8 units
  for (int idx = blockIdx.x * 256 + tid; idx < total; idx += gridDim.x * 256) {
    s16x8 v = h3b[idx];
    int k = (idx & 7) * 8;
    float4 o0, o1;
    o0.x = bf2f((unsigned short)v[0]) * lA[k]     + lC[k];
    o0.y = bf2f((unsigned short)v[1]) * lA[k + 1] + lC[k + 1];
    o0.z = bf2f((unsigned short)v[2]) * lA[k + 2] + lC[k + 2];
    o0.w = bf2f((unsigned short)v[3]) * lA[k + 3] + lC[k + 3];
    o1.x = bf2f((unsigned short)v[4]) * lA[k + 4] + lC[k + 4];
    o1.y = bf2f((unsigned short)v[5]) * lA[k + 5] + lC[k + 5];
    o1.z = bf2f((unsigned short)v[6]) * lA[k + 6] + lC[k + 6];
    o1.w = bf2f((unsigned short)v[7]) * lA[k + 7] + lC[k + 7];
    out[idx * 2]     = o0;
    out[idx * 2 + 1] = o1;
  }
}

extern "C" void kernel_launch(void* const* d_in, const int* in_sizes, int n_in,
                              void* d_out, int out_size, void* d_ws, size_t ws_size,
                              hipStream_t stream) {
  const float* x     = (const float*)d_in[0];
  const int*   ei    = (const int*)d_in[1];
  const float* state = (const float*)d_in[3];
  const int*   batch = (const int*)d_in[4];
  const float* W1  = (const float*)d_in[5];
  const float* b1  = (const float*)d_in[6];
  const float* g1  = (const float*)d_in[7];
  const float* be1 = (const float*)d_in[8];
  const float* W2  = (const float*)d_in[9];
  const float* b2  = (const float*)d_in[10];
  const float* g2  = (const float*)d_in[11];
  const float* be2 = (const float*)d_in[12];
  const float* W3  = (const float*)d_in[13];
  const float* b3  = (const float*)d_in[14];
  const float* g3  = (const float*)d_in[15];
  const float* be3 = (const float*)d_in[16];
  const float* ea  = (const float*)d_in[2];

  // Workspace layout:
  //   [0,       400000)  cnt
  //   [400000,  401536)  stats S1 Q1 S2 Q2 S3 Q3
  //   [401536,  409728)  w2f bf16       [409728, 409984) d2
  //   [409984,  418176)  w3f bf16       [418176, 418432) d3
  //   [418432, 26018432) eids (int, 64/node)   == h3 bf16 alias (12.8 MB)
  //   [26018432,38818432) vmb bf16 mean        == h2 bf16 alias
  //   [38818432,51618432) h1 bf16
  char* ws = (char*)d_ws;
  int*   cnt  = (int*)ws;
  float* S1   = (float*)(ws + 400000);
  float* Q1 = S1 + 64;
  float* S2 = S1 + 128;
  float* Q2 = S1 + 192;
  float* S3 = S1 + 256;
  float* Q3 = S1 + 320;
  unsigned short* w2f = (unsigned short*)(ws + 401536);
  float*          d2  = (float*)(ws + 409728);
  unsigned short* w3f = (unsigned short*)(ws + 409984);
  float*          d3  = (float*)(ws + 418176);
  int*            eids = (int*)(ws + 418432);
  unsigned short* h3b  = (unsigned short*)(ws + 418432);   // alias eids
  unsigned short* vmb  = (unsigned short*)(ws + 26018432);
  unsigned short* h2   = (unsigned short*)(ws + 26018432); // alias vmb
  unsigned short* h1   = (unsigned short*)(ws + 38818432);

  hipMemsetAsync(ws, 0, 401536, stream);   // cnt + stats

  k_bucket<<<NE / 256, 256, 0, stream>>>(ei, cnt, eids);
  k_gather<<<NN / 4, 256, 0, stream>>>(cnt, eids, (const float4*)ea, (ushort4*)vmb);

  const int nblk = (NN + 63) / 64;   // 1563
  k_g1<<<nblk, 256, 0, stream>>>((const float4*)x, (const ushort4*)vmb,
                                 (const float4*)state, batch, (const float4*)W1,
                                 b1, h1, S1, Q1);
  k_prep<<<1, 256, 0, stream>>>(S1, Q1, g1, be1, W2, b2, w2f, d2);
  k_gemm64<true><<<nblk, 256, 0, stream>>>(
      (const s16x8*)h1, (const s16x8*)w2f, d2, h2, S2, Q2);
  k_prep<<<1, 256, 0, stream>>>(S2, Q2, g2, be2, W3, b3, w3f, d3);
  k_gemm64<false><<<nblk, 256, 0, stream>>>(
      (const s16x8*)h2, (const s16x8*)w3f, d3, h3b, S3, Q3);
  k_bn3<<<2048, 256, 0, stream>>>((const s16x8*)h3b, g3, be3, S3, Q3, (float4*)d_out);
}